// Round 14
// baseline (153.400 us; speedup 1.0000x reference)
//
#include <hip/hip_runtime.h>
#include <hip/hip_bf16.h>
#include <math.h>

#define B_     2
#define T_     2048
#define D_     1024
#define H_     16
#define INNER_ 1024
#define NC_    4096       // combined GEMM N: 3072 qkv + 1024 gsp
#define SCALE_ 0.125f     // 64^-0.5, folded into Q at pointwise

typedef unsigned short u16;
typedef short short8 __attribute__((ext_vector_type(8)));
typedef float f32x4 __attribute__((ext_vector_type(4)));
typedef float f32x16 __attribute__((ext_vector_type(16)));
typedef unsigned short u16x4 __attribute__((ext_vector_type(4)));
typedef unsigned int u32x2 __attribute__((ext_vector_type(2)));

__device__ __forceinline__ u16 f2bf(float x) {
  union { float f; unsigned u; } v; v.f = x;
  unsigned r = v.u + 0x7fffu + ((v.u >> 16) & 1u);   // RNE, finite inputs
  return (u16)(r >> 16);
}
__device__ __forceinline__ float b2f(u16 x) {
  union { unsigned u; float f; } v; v.u = ((unsigned)x) << 16;
  return v.f;
}
// pack 2 f32 -> 2 bf16 in one VALU op (RNE)
__device__ __forceinline__ unsigned cvtpk(float lo, float hi) {
  unsigned r;
  asm("v_cvt_pk_bf16_f32 %0, %1, %2" : "=v"(r) : "v"(lo), "v"(hi));
  return r;
}
// async global->LDS, 16B per lane; LDS dest = wave-uniform base + lane*16
__device__ __forceinline__ void gload16(const void* g, void* l) {
  __builtin_amdgcn_global_load_lds(
      (const __attribute__((address_space(1))) void*)g,
      (__attribute__((address_space(3))) void*)l, 16, 0, 0);
}

// ---------------------------------------------------------------------------
// fused prep: [0,1280) weight transposes | [1280,1344) wdt | [1344,1600) rope
// | [1600,2624) cast x.  All branches block-uniform.
// ---------------------------------------------------------------------------
__global__ __launch_bounds__(256) void prep_kernel(
    const float* __restrict__ x, const float* __restrict__ W_qkv,
    const float* __restrict__ W_gsp, const float* __restrict__ W_out,
    const float* __restrict__ W_dt, const float* __restrict__ inv_freq,
    u16* __restrict__ xb, u16* __restrict__ Wcombt, u16* __restrict__ Woutt,
    u16* __restrict__ Wdtb, float2* __restrict__ tab) {
  const int bid = blockIdx.x, tid = threadIdx.x;
  if (bid < 1280) {   // 64x64 cast-transpose tiles, K=1024
    const float* src; u16* dst; int N, nx, ky;
    if (bid < 768)       { src = W_qkv; dst = Wcombt;                N = 3072; nx = bid % 48;          ky = bid / 48; }
    else if (bid < 1024) { src = W_gsp; dst = Wcombt + 3072 * 1024;  N = 1024; nx = (bid - 768) % 16;  ky = (bid - 768) / 16; }
    else                 { src = W_out; dst = Woutt;                 N = 1024; nx = (bid - 1024) % 16; ky = (bid - 1024) / 16; }
    __shared__ float tile[64][65];
    const int k0 = ky * 64, n0 = nx * 64;
    for (int e = tid; e < 4096; e += 256) {
      int kk = e >> 6, nn = e & 63;
      tile[kk][nn] = src[(size_t)(k0 + kk) * N + n0 + nn];
    }
    __syncthreads();
    for (int e = tid; e < 4096; e += 256) {
      int nn = e >> 6, kk = e & 63;
      dst[(size_t)(n0 + nn) * 1024 + k0 + kk] = f2bf(tile[kk][nn]);
    }
  } else if (bid < 1344) {   // W_dt [1024][16] -> Wdtb [16][1024]
    int i = (bid - 1280) * 256 + tid;
    int k = i >> 4, h = i & 15;
    Wdtb[(size_t)h * D_ + k] = f2bf(W_dt[i]);
  } else if (bid < 1600) {   // rope table
    int i = (bid - 1344) * 256 + tid;
    int t = i >> 5, j = i & 31;
    float s, c;
    sincosf((float)t * inv_freq[j], &s, &c);
    tab[i] = make_float2(c, s);
  } else {                   // cast x -> bf16, 4 float4 per thread
    int base = (bid - 1600) * 1024 + tid;
#pragma unroll
    for (int r = 0; r < 4; ++r) {
      int i = base + r * 256;
      float4 v = *reinterpret_cast<const float4*>(x + (size_t)i * 4);
      u16x4 o; o.x = f2bf(v.x); o.y = f2bf(v.y); o.z = f2bf(v.z); o.w = f2bf(v.w);
      *reinterpret_cast<u16x4*>(xb + (size_t)i * 4) = o;
    }
  }
}

// ---------------------------------------------------------------------------
// Big pipelined GEMM v4b (frozen): C(4096 x 4096) = A @ Bt^T, bf16 out.
// 128x256 tile, BK=32, 4 waves, 2 LDS slots (48KB), grid 512 = 2 blocks/CU.
// Rigorous sync: {vmcnt(0 own) -> barrier -> stage(kt+1) -> compute(kt)}.
// ---------------------------------------------------------------------------
__global__ __launch_bounds__(256, 2) void gemm_big(
    const u16* __restrict__ A, const u16* __restrict__ Bt,
    u16* __restrict__ C) {
  __shared__ u16 As[2][128 * 32] __attribute__((aligned(16)));  // 8KB each
  __shared__ u16 Bs[2][256 * 32] __attribute__((aligned(16)));  // 16KB each
  const int tid = threadIdx.x;
  const int w = tid >> 6, l = tid & 63;
  const int bid = blockIdx.x;             // 512 blocks: 32 brow x 16 bcol
  const int xcd = bid & 7, idx = bid >> 3;
  const int brow = xcd * 4 + (idx & 3);
  const int bcol = idx >> 2;
  const int m0 = brow * 128, n0 = bcol * 256;
  const int ql = l & 15, g4 = l >> 4;
  const int srow = tid >> 2;                // 0..63 (staging row within chunk)
  const int ssl  = (tid & 3) ^ (srow & 3);  // pre-swizzled k-slot

  const u16* Ag = A + (size_t)m0 * D_;
  const u16* Bg = Bt + (size_t)n0 * D_;

  auto STAGE = [&](int kt, int bp) {   // 6 gload16 per thread
#pragma unroll
    for (int c = 0; c < 2; ++c)
      gload16(Ag + (size_t)(c * 64 + srow) * D_ + kt * 32 + ssl * 8,
              (char*)As[bp] + c * 4096 + tid * 16);
#pragma unroll
    for (int c = 0; c < 4; ++c)
      gload16(Bg + (size_t)(c * 64 + srow) * D_ + kt * 32 + ssl * 8,
              (char*)Bs[bp] + c * 4096 + tid * 16);
  };

  f32x4 acc[8][4] = {};
  STAGE(0, 0);

  const int NT = D_ / 32;   // 32
  for (int kt = 0; kt < NT; ++kt) {
    const int bp = kt & 1;
    asm volatile("s_waitcnt vmcnt(0)" ::: "memory");   // own kt loads done
    __builtin_amdgcn_sched_barrier(0);
    __builtin_amdgcn_s_barrier();                      // => everyone's done
    __builtin_amdgcn_sched_barrier(0);
    if (kt + 1 < NT) STAGE(kt + 1, bp ^ 1);            // overlap with compute

    const char* Asb = (const char*)As[bp];
    const char* Bsb = (const char*)Bs[bp];
    short8 bf[4], af[4];
#pragma unroll
    for (int nf = 0; nf < 4; ++nf) {
      int row = w * 64 + nf * 16 + ql;
      bf[nf] = *(const short8*)(Bsb + row * 64 + ((g4 ^ (row & 3)) << 4));
    }
#pragma unroll
    for (int mf = 0; mf < 4; ++mf) {
      int row = mf * 16 + ql;
      af[mf] = *(const short8*)(Asb + row * 64 + ((g4 ^ (row & 3)) << 4));
    }
    __builtin_amdgcn_s_setprio(1);
#pragma unroll
    for (int mf = 0; mf < 4; ++mf)
#pragma unroll
      for (int nf = 0; nf < 4; ++nf)
        acc[mf][nf] = __builtin_amdgcn_mfma_f32_16x16x32_bf16(af[mf], bf[nf], acc[mf][nf], 0, 0, 0);
    __builtin_amdgcn_s_setprio(0);
#pragma unroll
    for (int mf = 0; mf < 4; ++mf) {
      int row = 64 + mf * 16 + ql;
      af[mf] = *(const short8*)(Asb + row * 64 + ((g4 ^ (row & 3)) << 4));
    }
    __builtin_amdgcn_s_setprio(1);
#pragma unroll
    for (int mf = 0; mf < 4; ++mf)
#pragma unroll
      for (int nf = 0; nf < 4; ++nf)
        acc[mf + 4][nf] = __builtin_amdgcn_mfma_f32_16x16x32_bf16(af[mf], bf[nf], acc[mf + 4][nf], 0, 0, 0);
    __builtin_amdgcn_s_setprio(0);
  }

#pragma unroll
  for (int mf = 0; mf < 8; ++mf) {
#pragma unroll
    for (int r = 0; r < 4; ++r) {
      size_t row = (size_t)(m0 + mf * 16 + g4 * 4 + r);
      size_t base = row * NC_ + n0 + w * 64 + ql;
#pragma unroll
      for (int nf = 0; nf < 4; ++nf)
        C[base + nf * 16] = f2bf(acc[mf][nf][r]);
    }
  }
}

// ---------------------------------------------------------------------------
// 128x128 GEMM (out-proj) v2 (frozen): rigorous 1-barrier pipeline, BK=64.
// ---------------------------------------------------------------------------
template <bool BF16OUT>
__global__ __launch_bounds__(256) void gemm_bt(
    const u16* __restrict__ A, const u16* __restrict__ Bt,
    void* __restrict__ Cv, int M, int N, int K) {
  __shared__ u16 As[2][128 * 64] __attribute__((aligned(16)));
  __shared__ u16 Bs[2][128 * 64] __attribute__((aligned(16)));
  const int tid = threadIdx.x, w = tid >> 6, l = tid & 63;
  const int rpx = (M >> 7) >> 3;            // rows per XCD (M=4096 -> 4)
  const int bid = blockIdx.x;
  const int xcd = bid & 7, idx = bid >> 3;
  const int brow = xcd * rpx + (idx % rpx);
  const int bcol = idx / rpx;
  const int m0 = brow * 128, n0 = bcol * 128;
  const int wr = (w >> 1) * 64, wc = (w & 1) * 64;
  const int srow = l >> 3;
  const int kgrp = ((l & 7) ^ srow) * 8;

  f32x4 acc[4][4] = {};

  auto stage = [&](int kt, int bs) {
#pragma unroll
    for (int i = 0; i < 4; ++i) {
      int c = w * 4 + i;
      int row = c * 8 + srow;
      gload16(A + (size_t)(m0 + row) * K + kt * 64 + kgrp, (char*)As[bs] + c * 1024);
      gload16(Bt + (size_t)(n0 + row) * K + kt * 64 + kgrp, (char*)Bs[bs] + c * 1024);
    }
  };

  stage(0, 0);
  const int NT = K >> 6;
  for (int kt = 0; kt < NT; ++kt) {
    asm volatile("s_waitcnt vmcnt(0)" ::: "memory");   // own kt loads done
    __builtin_amdgcn_sched_barrier(0);
    __builtin_amdgcn_s_barrier();                      // all waves' kt done
    __builtin_amdgcn_sched_barrier(0);
    if (kt + 1 < NT) stage(kt + 1, (kt + 1) & 1);      // overlap with compute

    const char* Asb = (const char*)As[kt & 1];
    const char* Bsb = (const char*)Bs[kt & 1];
#pragma unroll
    for (int kk = 0; kk < 2; ++kk) {
      short8 af[4], bf[4];
#pragma unroll
      for (int i = 0; i < 4; ++i) {
        int ra = wr + i * 16 + (l & 15);
        int sa = kk * 4 + (l >> 4);
        af[i] = *(const short8*)(Asb + ra * 128 + ((sa ^ (ra & 7)) << 4));
        int rb = wc + i * 16 + (l & 15);
        bf[i] = *(const short8*)(Bsb + rb * 128 + ((sa ^ (rb & 7)) << 4));
      }
#pragma unroll
      for (int i = 0; i < 4; ++i)
#pragma unroll
        for (int j = 0; j < 4; ++j)
          acc[i][j] = __builtin_amdgcn_mfma_f32_16x16x32_bf16(af[i], bf[j], acc[i][j], 0, 0, 0);
    }
  }
#pragma unroll
  for (int i = 0; i < 4; ++i) {
#pragma unroll
    for (int r = 0; r < 4; ++r) {
      size_t row = (size_t)(m0 + wr + i * 16 + (l >> 4) * 4 + r);
      size_t base = row * N + n0 + wc + (l & 15);
#pragma unroll
      for (int j = 0; j < 4; ++j) {
        if (BF16OUT) ((u16*)Cv)[base + j * 16] = f2bf(acc[i][j][r]);
        else         ((float*)Cv)[base + j * 16] = acc[i][j][r];
      }
    }
  }
}

// ---------------------------------------------------------------------------
// streaming pointwise + fused gamma: C [M][4096] = (q|k|v|praw). Wave/row.
// ---------------------------------------------------------------------------
__global__ __launch_bounds__(256) void pointwise_kernel(
    const u16* __restrict__ C, const u16* __restrict__ xb,
    const u16* __restrict__ Wdtb, const float* __restrict__ b_dt,
    const float* __restrict__ b_gsp, const float2* __restrict__ tab,
    u16* __restrict__ Qb, u16* __restrict__ Kb, u16* __restrict__ Vb,
    float* __restrict__ lg) {
  const int row = blockIdx.x * 4 + (threadIdx.x >> 6);
  const int l = threadIdx.x & 63;
  const int b = row >> 11, t = row & (T_ - 1);
  const int h = l >> 2;
  const int dd0 = (l & 3) * 16;
  const int col = h * 64 + dd0;
  const size_t cb = (size_t)row * NC_;

  // fused gamma
  float gsum = 0.f;
  {
    const int kc = (l & 3) * 256;
    const short8* xpg = (const short8*)(xb + (size_t)row * D_ + kc);
    const short8* wpg = (const short8*)(Wdtb + h * D_ + kc);
#pragma unroll
    for (int i = 0; i < 32; ++i) {
      short8 xv = xpg[i], wv = wpg[i];
#pragma unroll
      for (int j = 0; j < 8; ++j) gsum += b2f((u16)xv[j]) * b2f((u16)wv[j]);
    }
    gsum += __shfl_xor(gsum, 1);
    gsum += __shfl_xor(gsum, 2);
  }
  const float dtv = gsum + b_dt[h];
  const float sp = (dtv > 20.f) ? dtv : log1pf(__expf(dtv));
  const float gh = __expf(-sp);

  const short8* qp = (const short8*)(C + cb + col);
  const short8* kp = (const short8*)(C + cb + 1024 + col);
  const short8* vp = (const short8*)(C + cb + 2048 + col);
  const short8* pp = (const short8*)(C + cb + 3072 + col);
  short8 q0 = qp[0], q1 = qp[1];
  short8 k0 = kp[0], k1 = kp[1];
  short8 v0 = vp[0], v1 = vp[1];
  short8 pr0 = pp[0], pr1 = pp[1];

  float ge = 0.f;
  short8 vo0, vo1;
#pragma unroll
  for (int i = 0; i < 8; ++i) {
    float pv = b2f((u16)pr0[i]) + b_gsp[col + i];
    float p = 1.f / (1.f + __expf(-pv));
    ge += gh * (1.f - p) + p;
    vo0[i] = (short)f2bf(b2f((u16)v0[i]) * (1.f - p));
    float pv1 = b2f((u16)pr1[i]) + b_gsp[col + 8 + i];
    float p1 = 1.f / (1.f + __expf(-pv1));
    ge += gh * (1.f - p1) + p1;
    vo1[i] = (short)f2bf(b2f((u16)v1[i]) * (1.f - p1));
  }
  const size_t hm = (((size_t)(b * H_ + h)) * T_ + t) * 64 + dd0;
  ((short8*)(Vb + hm))[0] = vo0;
  ((short8*)(Vb + hm))[1] = vo1;

  ge += __shfl_xor(ge, 1);
  ge += __shfl_xor(ge, 2);
  if ((l & 3) == 0) {
    float gs = ge * (1.f / 64.f);
    gs = fminf(fmaxf(gs, 1e-6f), 1.f - 1e-6f);
    lg[((size_t)(b * H_ + h)) * T_ + t] = logf(gs);
  }

  short8 qo0, qo1, ko0, ko1;
  const float2* cs = tab + t * 32 + (dd0 >> 1);
#pragma unroll
  for (int m = 0; m < 4; ++m) {
    float2 c0 = cs[m];
    float qa = b2f((u16)q0[2 * m]), qb = b2f((u16)q0[2 * m + 1]);
    qo0[2 * m]     = (short)f2bf((qa * c0.x - qb * c0.y) * SCALE_);
    qo0[2 * m + 1] = (short)f2bf((qa * c0.y + qb * c0.x) * SCALE_);
    float ka = b2f((u16)k0[2 * m]), kb = b2f((u16)k0[2 * m + 1]);
    ko0[2 * m]     = (short)f2bf(ka * c0.x - kb * c0.y);
    ko0[2 * m + 1] = (short)f2bf(ka * c0.y + kb * c0.x);
    float2 c1 = cs[4 + m];
    float qa1 = b2f((u16)q1[2 * m]), qb1 = b2f((u16)q1[2 * m + 1]);
    qo1[2 * m]     = (short)f2bf((qa1 * c1.x - qb1 * c1.y) * SCALE_);
    qo1[2 * m + 1] = (short)f2bf((qa1 * c1.y + qb1 * c1.x) * SCALE_);
    float ka1 = b2f((u16)k1[2 * m]), kb1 = b2f((u16)k1[2 * m + 1]);
    ko1[2 * m]     = (short)f2bf(ka1 * c1.x - kb1 * c1.y);
    ko1[2 * m + 1] = (short)f2bf(ka1 * c1.y + kb1 * c1.x);
  }
  ((short8*)(Qb + hm))[0] = qo0; ((short8*)(Qb + hm))[1] = qo1;
  ((short8*)(Kb + hm))[0] = ko0; ((short8*)(Kb + hm))[1] = ko1;
}

// ---------------------------------------------------------------------------
// inclusive cumsum over T per (b,h)
// ---------------------------------------------------------------------------
__global__ __launch_bounds__(256) void scan_kernel(
    const float* __restrict__ lg, float* __restrict__ lgc) {
  const size_t base = (size_t)blockIdx.x * T_;
  const int tid = threadIdx.x;
  __shared__ float sums[256];
  float loc[8];
  float run = 0.f;
#pragma unroll
  for (int i = 0; i < 8; ++i) { run += lg[base + tid * 8 + i]; loc[i] = run; }
  sums[tid] = run;
  __syncthreads();
  if (tid == 0) {
    float r = 0.f;
    for (int i = 0; i < 256; ++i) { float v = sums[i]; sums[i] = r; r += v; }
  }
  __syncthreads();
  const float off = sums[tid];
#pragma unroll
  for (int i = 0; i < 8; ++i) lgc[base + tid * 8 + i] = off + loc[i];
}

// ---------------------------------------------------------------------------
// kv_prep: Vtg[bh][stile][dd][64] = V[bh][t][dd] * beta (tile-blocked V^T),
// beta = exp(lgc[tile_base] - lgc[t])
// ---------------------------------------------------------------------------
__global__ __launch_bounds__(256) void kv_prep_kernel(
    const u16* __restrict__ Vb, const float* __restrict__ lgc,
    u16* __restrict__ Vtg) {
  const int stile = blockIdx.x;
  const int bh = blockIdx.y;
  const int tid = threadIdx.x;
  __shared__ u16 vt[64][72];
  const size_t base = ((size_t)bh * T_ + (size_t)stile * 64) * 64;
  const float* lgp = lgc + (size_t)bh * T_;
  const float lgb = lgp[stile * 64];
#pragma unroll
  for (int i = 0; i < 2; ++i) {
    int c = tid * 2 + i;
    int row = c >> 3, k8 = (c & 7) * 8;
    float beta = __expf(lgb - lgp[stile * 64 + row]);
    short8 vv = *(const short8*)(Vb + base + row * 64 + k8);
#pragma unroll
    for (int j = 0; j < 8; ++j) vt[row][k8 + j] = f2bf(b2f((u16)vv[j]) * beta);
  }
  __syncthreads();
#pragma unroll
  for (int i = 0; i < 2; ++i) {
    int c = tid * 2 + i;
    int dd = c >> 3, t8 = (c & 7) * 8;
    short8 o;
#pragma unroll
    for (int j = 0; j < 8; ++j) o[j] = (short)vt[t8 + j][dd];
    *(short8*)(Vtg + ((size_t)(bh * 32 + stile) * 64 + dd) * 64 + t8) = o;
  }
}

// ---------------------------------------------------------------------------
// MFMA attention v7: 32x32x16, QBLK=256, 8 waves = (wq 0..3 x 64q) x (ws 0..1
// x 32s). Each K/V fragment feeds 2x the MFMA of v6 (wave covers 64 q),
// halving LDS-read per unit work; s-split keeps 2 waves/SIMD TLP. Cross-ws
// partial-Y reduction via LDS at epilogue. 3-slot ring, rigorous sync,
// in-register P (cvt_pk + permlane32_swap, HW-verified in v6).
// ---------------------------------------------------------------------------
__global__ __launch_bounds__(512) void attn_mfma(
    const u16* __restrict__ Qb, const u16* __restrict__ Kb,
    const u16* __restrict__ Vtg, const float* __restrict__ lgc,
    u16* __restrict__ Y) {
  const int i = blockIdx.x;            // 256 = 8 xcd * (8 qb * 4 bh_hi)
  const int xcd = i & 7;
  const int rr = i >> 3;               // 0..31
  const int qb = rr & 7;
  const int bh = xcd + ((rr >> 3) << 3);
  const int b = bh >> 4, h = bh & 15;
  const int tid = threadIdx.x, w = tid >> 6, l = tid & 63;
  const int wq = w & 3, ws = w >> 2;
  const int l31 = l & 31, hi = l >> 5;
  __shared__ char smem[3 * 16384] __attribute__((aligned(16)));  // K|V slots
  const u16* Qg = Qb + (size_t)bh * T_ * 64;
  const u16* Kg = Kb + (size_t)bh * T_ * 64;
  const u16* Vg = Vtg + (size_t)bh * 32 * 4096;
  const float* lgp = lgc + (size_t)bh * T_;
  const int srow = l >> 3, slot8 = l & 7;

  const int q0w = qb * 256 + wq * 64;       // wave q base (64 rows)
  const int qg0 = q0w + l31, qg1 = q0w + 32 + l31;
  short8 qf0[4], qf1[4];                    // Q B-frags per q-half
#pragma unroll
  for (int kk = 0; kk < 4; ++kk) {
    qf0[kk] = *(const short8*)(Qg + (size_t)qg0 * 64 + kk * 16 + hi * 8);
    qf1[kk] = *(const short8*)(Qg + (size_t)qg1 * 64 + kk * 16 + hi * 8);
  }
  const float lgq0 = lgp[qg0], lgq1 = lgp[qg1];
  const float lgtop = lgp[qb * 256];

  f32x16 yacc00 = {}, yacc01 = {}, yacc10 = {}, yacc11 = {};  // [qh][ddh]

  const int st0 = qb * 4 + 3;
  int s_min;
  {
    int lo = 0, hic = st0;
    while (lo < hic) {
      int mid = (lo + hic) >> 1;
      if (lgtop - lgp[mid * 64 + 63] > -20.f) hic = mid; else lo = mid + 1;
    }
    s_min = lo;
  }

  auto STAGE = [&](int s) {   // 2 gloads/thread; wave w stages chunk w
    char* base = smem + (s % 3) * 16384;
    int row = w * 8 + srow;
    int kg = (slot8 ^ (row & 7)) * 8;
    gload16(Kg + (size_t)(s * 64 + row) * 64 + kg, base + w * 1024);
    gload16(Vg + (size_t)s * 4096 + row * 64 + kg, base + 8192 + w * 1024);
  };

  STAGE(st0);
  if (st0 - 1 >= s_min) STAGE(st0 - 1);

  for (int st = st0; st >= s_min; --st) {
    if (st - 1 >= s_min) asm volatile("s_waitcnt vmcnt(2)" ::: "memory");
    else                 asm volatile("s_waitcnt vmcnt(0)" ::: "memory");
    __builtin_amdgcn_sched_barrier(0);
    __builtin_amdgcn_s_barrier();
    __builtin_amdgcn_sched_barrier(0);
    if (st - 2 >= s_min) STAGE(st - 2);

    const bool allinv = (st * 64 > q0w + 63);
    if (!allinv) {
      const char* Ksb = smem + (st % 3) * 16384;
      const char* Vsb = Ksb + 8192;
      const float alpha0 = __expf(lgq0 - lgp[st * 64]);
      const float alpha1 = __expf(lgq1 - lgp[st * 64]);
      const bool domask = (st * 64 + 63 > q0w);
      const int qrel0 = qg0 - st * 64, qrel1 = qg1 - st * 64;

      // QK^T for this wave's s-half (ws), both q-halves share kf
      short8 kf[4];
#pragma unroll
      for (int kk = 0; kk < 4; ++kk) {
        int row = ws * 32 + l31;
        kf[kk] = *(const short8*)(Ksb + row * 128 + (((kk * 2 + hi) ^ (row & 7)) << 4));
      }
      f32x16 c0 = {}, c1 = {};
      __builtin_amdgcn_s_setprio(1);
#pragma unroll
      for (int kk = 0; kk < 4; ++kk) {
        c0 = __builtin_amdgcn_mfma_f32_32x32x16_bf16(kf[kk], qf0[kk], c0, 0, 0, 0);
        c1 = __builtin_amdgcn_mfma_f32_32x32x16_bf16(kf[kk], qf1[kk], c1, 0, 0, 0);
      }
      __builtin_amdgcn_s_setprio(0);

      // V fragments for this ws (shared across q-halves)
      short8 vf00, vf01, vf10, vf11;   // [fi][ddh]
      {
        int r0 = l31, r1 = 32 + l31;
        int k0g = (ws * 2 + 0) * 2 + hi, k1g = (ws * 2 + 1) * 2 + hi;
        vf00 = *(const short8*)(Vsb + r0 * 128 + ((k0g ^ (r0 & 7)) << 4));
        vf01 = *(const short8*)(Vsb + r1 * 128 + ((k0g ^ (r1 & 7)) << 4));
        vf10 = *(const short8*)(Vsb + r0 * 128 + ((k1g ^ (r0 & 7)) << 4));
        vf11 = *(const short8*)(Vsb + r1 * 128 + ((k1g ^ (r1 & 7)) << 4));
      }

      // pack + PV per q-half (named blocks, no runtime indexing)
#define PACK_PV(CC, ALPHA, QREL, YA, YB)                                        \
      {                                                                          \
        float pv[16];                                                            \
        _Pragma("unroll")                                                        \
        for (int ii = 0; ii < 16; ++ii) {                                        \
          float p = (CC)[ii] * (ALPHA);                                          \
          if (domask) {                                                          \
            int s64 = ws * 32 + (ii & 3) + 8 * (ii >> 2) + 4 * hi;               \
            if (s64 > (QREL)) p = 0.f;                                           \
          }                                                                      \
          pv[ii] = p;                                                            \
        }                                                                        \
        unsigned A0 = cvtpk(pv[0], pv[1]),  A1 = cvtpk(pv[2], pv[3]);            \
        unsigned B0 = cvtpk(pv[4], pv[5]),  B1 = cvtpk(pv[6], pv[7]);            \
        u32x2 ra = __builtin_amdgcn_permlane32_swap(A0, B0, false, false);       \
        u32x2 rb = __builtin_amdgcn_permlane32_swap(A1, B1, false, false);       \
        unsigned C0 = cvtpk(pv[8], pv[9]),  C1 = cvtpk(pv[10], pv[11]);          \
        unsigned D0 = cvtpk(pv[12], pv[13]), D1 = cvtpk(pv[14], pv[15]);         \
        u32x2 rc = __builtin_amdgcn_permlane32_swap(C0, D0, false, false);       \
        u32x2 rd = __builtin_amdgcn_permlane32_swap(C1, D1, false, false);       \
        union { unsigned u[4]; short8 s; } f0, f1;                               \
        f0.u[0] = ra[0]; f0.u[1] = rb[0]; f0.u[2] = ra[1]; f0.u[3] = rb[1];      \
        f1.u[0] = rc[0]; f1.u[1] = rd[0]; f1.u[2] = rc[1]; f1.u[3] = rd[1];      \
        __builtin_amdgcn_s_setprio(1);                                           \
        YA = __builtin_amdgcn_mfma_f32_32x32x16_bf16(f0.s, vf00, YA, 0, 0, 0);   \
        YB = __builtin_amdgcn_mfma_f32_32x32x16_bf16(f0.s, vf01, YB, 0, 0, 0);   \
        YA = __builtin_amdgcn_mfma_f32_32x32x16_bf16(f1.s, vf10, YA, 0, 0, 0);   \
        YB = __builtin_amdgcn_mfma_f32_32x32x16_bf16(f1.s, vf11, YB, 0, 0, 0);   \
        __builtin_amdgcn_s_setprio(0);                                           \
      }
      PACK_PV(c0, alpha0, qrel0, yacc00, yacc01)
      PACK_PV(c1, alpha1, qrel1, yacc10, yacc11)
#undef PACK_PV
    }
  }

  // cross-ws reduction: ws=1 partials -> ws=0 via LDS (2 passes of 32KB)
#define REDUCE(YA, YB)                                                           \
  {                                                                              \
    __syncthreads();                                                             \
    if (ws == 1) {                                                               \
      *(f32x16*)(smem + wq * 8192 + l * 128)      = YA;                          \
      *(f32x16*)(smem + wq * 8192 + l * 128 + 64) = YB;                          \
    }                                                                            \
    __syncthreads();                                                             \
    if (ws == 0) {                                                               \
      YA += *(const f32x16*)(smem + wq * 8192 + l * 128);                        \
      YB += *(const f32x16*)(smem + wq * 8192 + l * 128 + 64);                   \
    }                                                                            \
  }
  REDUCE(yacc00, yacc01)
  REDUCE(yacc10, yacc11)
#undef REDUCE

  if (ws == 0) {
#pragma unroll
    for (int reg = 0; reg < 16; ++reg) {
      int qrow = (reg & 3) + 8 * (reg >> 2) + 4 * hi;
      size_t r0 = (size_t)(b * T_) + q0w + qrow;
      size_t r1 = r0 + 32;
      Y[r0 * INNER_ + h * 64 + l31]      = f2bf(yacc00[reg]);
      Y[r0 * INNER_ + h * 64 + 32 + l31] = f2bf(yacc01[reg]);
      Y[r1 * INNER_ + h * 64 + l31]      = f2bf(yacc10[reg]);
      Y[r1 * INNER_ + h * 64 + 32 + l31] = f2bf(yacc11[reg]);
    }
  }
}

// ---------------------------------------------------------------------------
extern "C" void kernel_launch(void* const* d_in, const int* in_sizes, int n_in,
                              void* d_out, int out_size, void* d_ws, size_t ws_size,
                              hipStream_t stream) {
  const float* x        = (const float*)d_in[0];
  const float* W_qkv    = (const float*)d_in[1];
  const float* W_out    = (const float*)d_in[2];
  const float* W_dt     = (const float*)d_in[3];
  const float* b_dt     = (const float*)d_in[4];
  const float* W_gsp    = (const float*)d_in[5];
  const float* b_gsp    = (const float*)d_in[6];
  const float* inv_freq = (const float*)d_in[7];
  float* out = (float*)d_out;

  const int M = B_ * T_;  // 4096
  char* p = (char*)d_ws;
  auto alloc = [&](size_t bytes) {
    char* r = p; p += (bytes + 255) & ~(size_t)255; return r;
  };
  u16*    xb    = (u16*)alloc((size_t)M * D_ * 2);             // 8 MB
  u16*    Wcombt= (u16*)alloc((size_t)NC_ * D_ * 2);           // 8 MB
  u16*    Woutt = (u16*)alloc((size_t)D_ * INNER_ * 2);        // 2 MB
  u16*    Wdtb  = (u16*)alloc((size_t)H_ * D_ * 2);            // 32 KB
  u16*    Cqkvp = (u16*)alloc((size_t)M * NC_ * 2);            // 32 MB
  u16*    Qb    = (u16*)alloc((size_t)B_ * H_ * T_ * 64 * 2);  // 8 MB
  u16*    Kb    = (u16*)alloc((size_t)B_ * H_ * T_ * 64 * 2);
  u16*    Vb    = (u16*)alloc((size_t)B_ * H_ * T_ * 64 * 2);
  float*  lg    = (float*)alloc((size_t)B_ * H_ * T_ * 4);
  float*  lgc   = (float*)alloc((size_t)B_ * H_ * T_ * 4);
  float2* tab   = (float2*)alloc((size_t)T_ * 32 * 8);         // 512 KB
  // after pointwise, Cqkvp is dead -> alias attention buffers into it
  u16*    Vtg   = Cqkvp;                                       // 8 MB
  u16*    Yb    = Cqkvp + (size_t)4 * 1024 * 1024;             // 8 MB

  // fused prep (casts, transposes, rope table)
  prep_kernel<<<2624, 256, 0, stream>>>(x, W_qkv, W_gsp, W_out, W_dt, inv_freq,
                                        xb, Wcombt, Woutt, Wdtb, tab);
  // combined projection GEMM: [q|k|v|praw] = x @ [W_qkv|W_gsp]  (N=4096)
  gemm_big<<<512, 256, 0, stream>>>(xb, Wcombt, Cqkvp);

  pointwise_kernel<<<M / 4, 256, 0, stream>>>(Cqkvp, xb, Wdtb, b_dt, b_gsp,
                                              tab, Qb, Kb, Vb, lg);
  scan_kernel<<<B_ * H_, 256, 0, stream>>>(lg, lgc);
  kv_prep_kernel<<<dim3(T_ / 64, B_ * H_), 256, 0, stream>>>(Vb, lgc, Vtg);

  attn_mfma<<<256, 512, 0, stream>>>(Qb, Kb, Vtg, lgc, Yb);

  // out = Y @ W_out  (fp32 out)
  gemm_bt<false><<<256, 256, 0, stream>>>(Yb, Woutt, out, M, D_, INNER_);
}

// Round 15
// 148.468 us; speedup vs baseline: 1.0332x; 1.0332x over previous
//
#include <hip/hip_runtime.h>
#include <hip/hip_bf16.h>
#include <math.h>

#define B_     2
#define T_     2048
#define D_     1024
#define H_     16
#define INNER_ 1024
#define NC_    4096       // combined GEMM N: 3072 qkv + 1024 gsp
#define SCALE_ 0.125f     // 64^-0.5, folded into Q at pointwise

typedef unsigned short u16;
typedef short short8 __attribute__((ext_vector_type(8)));
typedef float f32x4 __attribute__((ext_vector_type(4)));
typedef float f32x16 __attribute__((ext_vector_type(16)));
typedef unsigned short u16x4 __attribute__((ext_vector_type(4)));
typedef unsigned int u32x2 __attribute__((ext_vector_type(2)));

__device__ __forceinline__ u16 f2bf(float x) {
  union { float f; unsigned u; } v; v.f = x;
  unsigned r = v.u + 0x7fffu + ((v.u >> 16) & 1u);   // RNE, finite inputs
  return (u16)(r >> 16);
}
__device__ __forceinline__ float b2f(u16 x) {
  union { unsigned u; float f; } v; v.u = ((unsigned)x) << 16;
  return v.f;
}
// pack 2 f32 -> 2 bf16 in one VALU op (RNE)
__device__ __forceinline__ unsigned cvtpk(float lo, float hi) {
  unsigned r;
  asm("v_cvt_pk_bf16_f32 %0, %1, %2" : "=v"(r) : "v"(lo), "v"(hi));
  return r;
}
// async global->LDS, 16B per lane; LDS dest = wave-uniform base + lane*16
__device__ __forceinline__ void gload16(const void* g, void* l) {
  __builtin_amdgcn_global_load_lds(
      (const __attribute__((address_space(1))) void*)g,
      (__attribute__((address_space(3))) void*)l, 16, 0, 0);
}

// ---------------------------------------------------------------------------
// fused prep: [0,1280) weight transposes | [1280,1344) wdt | [1344,1600) rope
// | [1600,2624) cast x.  All branches block-uniform.
// ---------------------------------------------------------------------------
__global__ __launch_bounds__(256) void prep_kernel(
    const float* __restrict__ x, const float* __restrict__ W_qkv,
    const float* __restrict__ W_gsp, const float* __restrict__ W_out,
    const float* __restrict__ W_dt, const float* __restrict__ inv_freq,
    u16* __restrict__ xb, u16* __restrict__ Wcombt, u16* __restrict__ Woutt,
    u16* __restrict__ Wdtb, float2* __restrict__ tab) {
  const int bid = blockIdx.x, tid = threadIdx.x;
  if (bid < 1280) {   // 64x64 cast-transpose tiles, K=1024
    const float* src; u16* dst; int N, nx, ky;
    if (bid < 768)       { src = W_qkv; dst = Wcombt;                N = 3072; nx = bid % 48;          ky = bid / 48; }
    else if (bid < 1024) { src = W_gsp; dst = Wcombt + 3072 * 1024;  N = 1024; nx = (bid - 768) % 16;  ky = (bid - 768) / 16; }
    else                 { src = W_out; dst = Woutt;                 N = 1024; nx = (bid - 1024) % 16; ky = (bid - 1024) / 16; }
    __shared__ float tile[64][65];
    const int k0 = ky * 64, n0 = nx * 64;
    for (int e = tid; e < 4096; e += 256) {
      int kk = e >> 6, nn = e & 63;
      tile[kk][nn] = src[(size_t)(k0 + kk) * N + n0 + nn];
    }
    __syncthreads();
    for (int e = tid; e < 4096; e += 256) {
      int nn = e >> 6, kk = e & 63;
      dst[(size_t)(n0 + nn) * 1024 + k0 + kk] = f2bf(tile[kk][nn]);
    }
  } else if (bid < 1344) {   // W_dt [1024][16] -> Wdtb [16][1024]
    int i = (bid - 1280) * 256 + tid;
    int k = i >> 4, h = i & 15;
    Wdtb[(size_t)h * D_ + k] = f2bf(W_dt[i]);
  } else if (bid < 1600) {   // rope table
    int i = (bid - 1344) * 256 + tid;
    int t = i >> 5, j = i & 31;
    float s, c;
    sincosf((float)t * inv_freq[j], &s, &c);
    tab[i] = make_float2(c, s);
  } else {                   // cast x -> bf16, 4 float4 per thread
    int base = (bid - 1600) * 1024 + tid;
#pragma unroll
    for (int r = 0; r < 4; ++r) {
      int i = base + r * 256;
      float4 v = *reinterpret_cast<const float4*>(x + (size_t)i * 4);
      u16x4 o; o.x = f2bf(v.x); o.y = f2bf(v.y); o.z = f2bf(v.z); o.w = f2bf(v.w);
      *reinterpret_cast<u16x4*>(xb + (size_t)i * 4) = o;
    }
  }
}

// ---------------------------------------------------------------------------
// Big pipelined GEMM v4b (frozen): C(4096 x 4096) = A @ Bt^T, bf16 out.
// 128x256 tile, BK=32, 4 waves, 2 LDS slots (48KB), grid 512 = 2 blocks/CU.
// Rigorous sync: {vmcnt(0 own) -> barrier -> stage(kt+1) -> compute(kt)}.
// ---------------------------------------------------------------------------
__global__ __launch_bounds__(256, 2) void gemm_big(
    const u16* __restrict__ A, const u16* __restrict__ Bt,
    u16* __restrict__ C) {
  __shared__ u16 As[2][128 * 32] __attribute__((aligned(16)));  // 8KB each
  __shared__ u16 Bs[2][256 * 32] __attribute__((aligned(16)));  // 16KB each
  const int tid = threadIdx.x;
  const int w = tid >> 6, l = tid & 63;
  const int bid = blockIdx.x;             // 512 blocks: 32 brow x 16 bcol
  const int xcd = bid & 7, idx = bid >> 3;
  const int brow = xcd * 4 + (idx & 3);
  const int bcol = idx >> 2;
  const int m0 = brow * 128, n0 = bcol * 256;
  const int ql = l & 15, g4 = l >> 4;
  const int srow = tid >> 2;                // 0..63 (staging row within chunk)
  const int ssl  = (tid & 3) ^ (srow & 3);  // pre-swizzled k-slot

  const u16* Ag = A + (size_t)m0 * D_;
  const u16* Bg = Bt + (size_t)n0 * D_;

  auto STAGE = [&](int kt, int bp) {   // 6 gload16 per thread
#pragma unroll
    for (int c = 0; c < 2; ++c)
      gload16(Ag + (size_t)(c * 64 + srow) * D_ + kt * 32 + ssl * 8,
              (char*)As[bp] + c * 4096 + tid * 16);
#pragma unroll
    for (int c = 0; c < 4; ++c)
      gload16(Bg + (size_t)(c * 64 + srow) * D_ + kt * 32 + ssl * 8,
              (char*)Bs[bp] + c * 4096 + tid * 16);
  };

  f32x4 acc[8][4] = {};
  STAGE(0, 0);

  const int NT = D_ / 32;   // 32
  for (int kt = 0; kt < NT; ++kt) {
    const int bp = kt & 1;
    asm volatile("s_waitcnt vmcnt(0)" ::: "memory");   // own kt loads done
    __builtin_amdgcn_sched_barrier(0);
    __builtin_amdgcn_s_barrier();                      // => everyone's done
    __builtin_amdgcn_sched_barrier(0);
    if (kt + 1 < NT) STAGE(kt + 1, bp ^ 1);            // overlap with compute

    const char* Asb = (const char*)As[bp];
    const char* Bsb = (const char*)Bs[bp];
    short8 bf[4], af[4];
#pragma unroll
    for (int nf = 0; nf < 4; ++nf) {
      int row = w * 64 + nf * 16 + ql;
      bf[nf] = *(const short8*)(Bsb + row * 64 + ((g4 ^ (row & 3)) << 4));
    }
#pragma unroll
    for (int mf = 0; mf < 4; ++mf) {
      int row = mf * 16 + ql;
      af[mf] = *(const short8*)(Asb + row * 64 + ((g4 ^ (row & 3)) << 4));
    }
    __builtin_amdgcn_s_setprio(1);
#pragma unroll
    for (int mf = 0; mf < 4; ++mf)
#pragma unroll
      for (int nf = 0; nf < 4; ++nf)
        acc[mf][nf] = __builtin_amdgcn_mfma_f32_16x16x32_bf16(af[mf], bf[nf], acc[mf][nf], 0, 0, 0);
    __builtin_amdgcn_s_setprio(0);
#pragma unroll
    for (int mf = 0; mf < 4; ++mf) {
      int row = 64 + mf * 16 + ql;
      af[mf] = *(const short8*)(Asb + row * 64 + ((g4 ^ (row & 3)) << 4));
    }
    __builtin_amdgcn_s_setprio(1);
#pragma unroll
    for (int mf = 0; mf < 4; ++mf)
#pragma unroll
      for (int nf = 0; nf < 4; ++nf)
        acc[mf + 4][nf] = __builtin_amdgcn_mfma_f32_16x16x32_bf16(af[mf], bf[nf], acc[mf + 4][nf], 0, 0, 0);
    __builtin_amdgcn_s_setprio(0);
  }

#pragma unroll
  for (int mf = 0; mf < 8; ++mf) {
#pragma unroll
    for (int r = 0; r < 4; ++r) {
      size_t row = (size_t)(m0 + mf * 16 + g4 * 4 + r);
      size_t base = row * NC_ + n0 + w * 64 + ql;
#pragma unroll
      for (int nf = 0; nf < 4; ++nf)
        C[base + nf * 16] = f2bf(acc[mf][nf][r]);
    }
  }
}

// ---------------------------------------------------------------------------
// 128x128 GEMM (out-proj) v2 (frozen): rigorous 1-barrier pipeline, BK=64.
// ---------------------------------------------------------------------------
template <bool BF16OUT>
__global__ __launch_bounds__(256) void gemm_bt(
    const u16* __restrict__ A, const u16* __restrict__ Bt,
    void* __restrict__ Cv, int M, int N, int K) {
  __shared__ u16 As[2][128 * 64] __attribute__((aligned(16)));
  __shared__ u16 Bs[2][128 * 64] __attribute__((aligned(16)));
  const int tid = threadIdx.x, w = tid >> 6, l = tid & 63;
  const int rpx = (M >> 7) >> 3;            // rows per XCD (M=4096 -> 4)
  const int bid = blockIdx.x;
  const int xcd = bid & 7, idx = bid >> 3;
  const int brow = xcd * rpx + (idx % rpx);
  const int bcol = idx / rpx;
  const int m0 = brow * 128, n0 = bcol * 128;
  const int wr = (w >> 1) * 64, wc = (w & 1) * 64;
  const int srow = l >> 3;
  const int kgrp = ((l & 7) ^ srow) * 8;

  f32x4 acc[4][4] = {};

  auto stage = [&](int kt, int bs) {
#pragma unroll
    for (int i = 0; i < 4; ++i) {
      int c = w * 4 + i;
      int row = c * 8 + srow;
      gload16(A + (size_t)(m0 + row) * K + kt * 64 + kgrp, (char*)As[bs] + c * 1024);
      gload16(Bt + (size_t)(n0 + row) * K + kt * 64 + kgrp, (char*)Bs[bs] + c * 1024);
    }
  };

  stage(0, 0);
  const int NT = K >> 6;
  for (int kt = 0; kt < NT; ++kt) {
    asm volatile("s_waitcnt vmcnt(0)" ::: "memory");   // own kt loads done
    __builtin_amdgcn_sched_barrier(0);
    __builtin_amdgcn_s_barrier();                      // all waves' kt done
    __builtin_amdgcn_sched_barrier(0);
    if (kt + 1 < NT) stage(kt + 1, (kt + 1) & 1);      // overlap with compute

    const char* Asb = (const char*)As[kt & 1];
    const char* Bsb = (const char*)Bs[kt & 1];
#pragma unroll
    for (int kk = 0; kk < 2; ++kk) {
      short8 af[4], bf[4];
#pragma unroll
      for (int i = 0; i < 4; ++i) {
        int ra = wr + i * 16 + (l & 15);
        int sa = kk * 4 + (l >> 4);
        af[i] = *(const short8*)(Asb + ra * 128 + ((sa ^ (ra & 7)) << 4));
        int rb = wc + i * 16 + (l & 15);
        bf[i] = *(const short8*)(Bsb + rb * 128 + ((sa ^ (rb & 7)) << 4));
      }
#pragma unroll
      for (int i = 0; i < 4; ++i)
#pragma unroll
        for (int j = 0; j < 4; ++j)
          acc[i][j] = __builtin_amdgcn_mfma_f32_16x16x32_bf16(af[i], bf[j], acc[i][j], 0, 0, 0);
    }
  }
#pragma unroll
  for (int i = 0; i < 4; ++i) {
#pragma unroll
    for (int r = 0; r < 4; ++r) {
      size_t row = (size_t)(m0 + wr + i * 16 + (l >> 4) * 4 + r);
      size_t base = row * N + n0 + wc + (l & 15);
#pragma unroll
      for (int j = 0; j < 4; ++j) {
        if (BF16OUT) ((u16*)Cv)[base + j * 16] = f2bf(acc[i][j][r]);
        else         ((float*)Cv)[base + j * 16] = acc[i][j][r];
      }
    }
  }
}

// ---------------------------------------------------------------------------
// streaming pointwise + fused gamma: C [M][4096] = (q|k|v|praw). Wave/row.
// ---------------------------------------------------------------------------
__global__ __launch_bounds__(256) void pointwise_kernel(
    const u16* __restrict__ C, const u16* __restrict__ xb,
    const u16* __restrict__ Wdtb, const float* __restrict__ b_dt,
    const float* __restrict__ b_gsp, const float2* __restrict__ tab,
    u16* __restrict__ Qb, u16* __restrict__ Kb, u16* __restrict__ Vb,
    float* __restrict__ lg) {
  const int row = blockIdx.x * 4 + (threadIdx.x >> 6);
  const int l = threadIdx.x & 63;
  const int b = row >> 11, t = row & (T_ - 1);
  const int h = l >> 2;
  const int dd0 = (l & 3) * 16;
  const int col = h * 64 + dd0;
  const size_t cb = (size_t)row * NC_;

  // fused gamma
  float gsum = 0.f;
  {
    const int kc = (l & 3) * 256;
    const short8* xpg = (const short8*)(xb + (size_t)row * D_ + kc);
    const short8* wpg = (const short8*)(Wdtb + h * D_ + kc);
#pragma unroll
    for (int i = 0; i < 32; ++i) {
      short8 xv = xpg[i], wv = wpg[i];
#pragma unroll
      for (int j = 0; j < 8; ++j) gsum += b2f((u16)xv[j]) * b2f((u16)wv[j]);
    }
    gsum += __shfl_xor(gsum, 1);
    gsum += __shfl_xor(gsum, 2);
  }
  const float dtv = gsum + b_dt[h];
  const float sp = (dtv > 20.f) ? dtv : log1pf(__expf(dtv));
  const float gh = __expf(-sp);

  const short8* qp = (const short8*)(C + cb + col);
  const short8* kp = (const short8*)(C + cb + 1024 + col);
  const short8* vp = (const short8*)(C + cb + 2048 + col);
  const short8* pp = (const short8*)(C + cb + 3072 + col);
  short8 q0 = qp[0], q1 = qp[1];
  short8 k0 = kp[0], k1 = kp[1];
  short8 v0 = vp[0], v1 = vp[1];
  short8 pr0 = pp[0], pr1 = pp[1];

  float ge = 0.f;
  short8 vo0, vo1;
#pragma unroll
  for (int i = 0; i < 8; ++i) {
    float pv = b2f((u16)pr0[i]) + b_gsp[col + i];
    float p = 1.f / (1.f + __expf(-pv));
    ge += gh * (1.f - p) + p;
    vo0[i] = (short)f2bf(b2f((u16)v0[i]) * (1.f - p));
    float pv1 = b2f((u16)pr1[i]) + b_gsp[col + 8 + i];
    float p1 = 1.f / (1.f + __expf(-pv1));
    ge += gh * (1.f - p1) + p1;
    vo1[i] = (short)f2bf(b2f((u16)v1[i]) * (1.f - p1));
  }
  const size_t hm = (((size_t)(b * H_ + h)) * T_ + t) * 64 + dd0;
  ((short8*)(Vb + hm))[0] = vo0;
  ((short8*)(Vb + hm))[1] = vo1;

  ge += __shfl_xor(ge, 1);
  ge += __shfl_xor(ge, 2);
  if ((l & 3) == 0) {
    float gs = ge * (1.f / 64.f);
    gs = fminf(fmaxf(gs, 1e-6f), 1.f - 1e-6f);
    lg[((size_t)(b * H_ + h)) * T_ + t] = logf(gs);
  }

  short8 qo0, qo1, ko0, ko1;
  const float2* cs = tab + t * 32 + (dd0 >> 1);
#pragma unroll
  for (int m = 0; m < 4; ++m) {
    float2 c0 = cs[m];
    float qa = b2f((u16)q0[2 * m]), qb = b2f((u16)q0[2 * m + 1]);
    qo0[2 * m]     = (short)f2bf((qa * c0.x - qb * c0.y) * SCALE_);
    qo0[2 * m + 1] = (short)f2bf((qa * c0.y + qb * c0.x) * SCALE_);
    float ka = b2f((u16)k0[2 * m]), kb = b2f((u16)k0[2 * m + 1]);
    ko0[2 * m]     = (short)f2bf(ka * c0.x - kb * c0.y);
    ko0[2 * m + 1] = (short)f2bf(ka * c0.y + kb * c0.x);
    float2 c1 = cs[4 + m];
    float qa1 = b2f((u16)q1[2 * m]), qb1 = b2f((u16)q1[2 * m + 1]);
    qo1[2 * m]     = (short)f2bf((qa1 * c1.x - qb1 * c1.y) * SCALE_);
    qo1[2 * m + 1] = (short)f2bf((qa1 * c1.y + qb1 * c1.x) * SCALE_);
    float ka1 = b2f((u16)k1[2 * m]), kb1 = b2f((u16)k1[2 * m + 1]);
    ko1[2 * m]     = (short)f2bf(ka1 * c1.x - kb1 * c1.y);
    ko1[2 * m + 1] = (short)f2bf(ka1 * c1.y + kb1 * c1.x);
  }
  ((short8*)(Qb + hm))[0] = qo0; ((short8*)(Qb + hm))[1] = qo1;
  ((short8*)(Kb + hm))[0] = ko0; ((short8*)(Kb + hm))[1] = ko1;
}

// ---------------------------------------------------------------------------
// scan+kv_prep merged: block (stile, bh). Each block redundantly computes the
// full inclusive prefix of lg[bh][:] (2048 elems, trivial), stile==0 writes
// lgc; all blocks build Vtg[bh][stile] = V * beta (tile-blocked V^T).
// ---------------------------------------------------------------------------
__global__ __launch_bounds__(256) void kv_prep_kernel(
    const u16* __restrict__ Vb, const float* __restrict__ lg,
    float* __restrict__ lgc, u16* __restrict__ Vtg) {
  const int stile = blockIdx.x;
  const int bh = blockIdx.y;
  const int tid = threadIdx.x;
  __shared__ u16 vt[64][72];
  __shared__ float sums[256];
  __shared__ float lgs[T_];          // full lgc row for this bh (8KB)
  const size_t lbase = (size_t)bh * T_;

  // in-block scan of lg[bh][:]
  float loc[8];
  {
    float run = 0.f;
#pragma unroll
    for (int i = 0; i < 8; ++i) { run += lg[lbase + tid * 8 + i]; loc[i] = run; }
    sums[tid] = run;
  }
  __syncthreads();
  if (tid == 0) {
    float r = 0.f;
    for (int i = 0; i < 256; ++i) { float v = sums[i]; sums[i] = r; r += v; }
  }
  __syncthreads();
  {
    const float off = sums[tid];
#pragma unroll
    for (int i = 0; i < 8; ++i) lgs[tid * 8 + i] = off + loc[i];
  }
  __syncthreads();
  if (stile == 0) {   // one writer per bh
#pragma unroll
    for (int i = 0; i < 8; ++i) lgc[lbase + tid * 8 + i] = lgs[tid * 8 + i];
  }

  const size_t base = (lbase + (size_t)stile * 64) * 64;
  const float lgb = lgs[stile * 64];
#pragma unroll
  for (int i = 0; i < 2; ++i) {
    int c = tid * 2 + i;
    int row = c >> 3, k8 = (c & 7) * 8;
    float beta = __expf(lgb - lgs[stile * 64 + row]);
    short8 vv = *(const short8*)(Vb + base + row * 64 + k8);
#pragma unroll
    for (int j = 0; j < 8; ++j) vt[row][k8 + j] = f2bf(b2f((u16)vv[j]) * beta);
  }
  __syncthreads();
#pragma unroll
  for (int i = 0; i < 2; ++i) {
    int c = tid * 2 + i;
    int dd = c >> 3, t8 = (c & 7) * 8;
    short8 o;
#pragma unroll
    for (int j = 0; j < 8; ++j) o[j] = (short)vt[t8 + j][dd];
    *(short8*)(Vtg + ((size_t)(bh * 32 + stile) * 64 + dd) * 64 + t8) = o;
  }
}

// ---------------------------------------------------------------------------
// MFMA attention v5r (best measured body + rigorous sync): 32x32x16,
// QBLK=128, 3-slot ring (48KB), {vmcnt(own) -> barrier -> stage}, per-wave
// Ps LDS, cvt_pk pack, mask only on diagonal tiles, decay-window s_min,
// complementary-qb CU pairing.
// ---------------------------------------------------------------------------
__global__ __launch_bounds__(256) void attn_mfma(
    const u16* __restrict__ Qb, const u16* __restrict__ Kb,
    const u16* __restrict__ Vtg, const float* __restrict__ lgc,
    u16* __restrict__ Y) {
  const int i = blockIdx.x;            // 512
  const int xcd = i & 7;
  const int half = i >> 8;             // complementary halves share a CU
  const int r = (i >> 3) & 31;
  const int q8 = r >> 2;
  const int bh_hi = r & 3;
  const int qb = half ? (15 - q8) : q8;
  const int bh = xcd + (bh_hi << 3);
  const int b = bh >> 4, h = bh & 15;
  const int tid = threadIdx.x, w = tid >> 6, l = tid & 63;
  const int l31 = l & 31, hi = l >> 5;
  __shared__ u16 Ks[3][64 * 64] __attribute__((aligned(16)));
  __shared__ u16 Vs[3][64 * 64] __attribute__((aligned(16)));
  __shared__ u16 Ps[4][2048] __attribute__((aligned(16)));   // per-wave 32x64
  const u16* Qg = Qb + (size_t)bh * T_ * 64;
  const u16* Kg = Kb + (size_t)bh * T_ * 64;
  const u16* Vg = Vtg + (size_t)bh * 32 * 4096;
  const float* lgp = lgc + (size_t)bh * T_;
  const int srow = l >> 3, slot8 = l & 7;

  const int q0 = qb * 128 + w * 32;     // wave q base
  const int qg = q0 + l31;              // lane q row
  short8 qf[4];                          // Q B-frags: col=q, k=kk*16+hi*8
#pragma unroll
  for (int kk = 0; kk < 4; ++kk)
    qf[kk] = *(const short8*)(Qg + (size_t)qg * 64 + kk * 16 + hi * 8);
  const float lgq = lgp[qg];
  const float lgtop = lgp[qb * 128];

  char* Pw = (char*)Ps[w];
  const int psw = l31 & 7;

  f32x16 yacc0 = {}, yacc1 = {};

  const int st0 = qb * 2 + 1;
  int s_min;
  {
    int lo = 0, hic = st0;
    while (lo < hic) {
      int mid = (lo + hic) >> 1;
      if (lgtop - lgp[mid * 64 + 63] > -20.f) hic = mid; else lo = mid + 1;
    }
    s_min = lo;
  }

  auto STAGE = [&](int s) {   // 4 gloads/thread
    const int bs = s % 3;
#pragma unroll
    for (int i2 = 0; i2 < 2; ++i2) {
      int c = w * 2 + i2, row = c * 8 + srow;
      int kg = (slot8 ^ (row & 7)) * 8;
      gload16(Kg + (size_t)(s * 64 + row) * 64 + kg, (char*)Ks[bs] + c * 1024);
      gload16(Vg + (size_t)s * 4096 + row * 64 + kg, (char*)Vs[bs] + c * 1024);
    }
  };

  STAGE(st0);
  if (st0 - 1 >= s_min) STAGE(st0 - 1);

  for (int st = st0; st >= s_min; --st) {
    // rigorous: drain OWN st loads, then barrier => all waves' st loads done
    if (st - 1 >= s_min) asm volatile("s_waitcnt vmcnt(4)" ::: "memory");
    else                 asm volatile("s_waitcnt vmcnt(0)" ::: "memory");
    __builtin_amdgcn_sched_barrier(0);
    __builtin_amdgcn_s_barrier();
    __builtin_amdgcn_sched_barrier(0);
    if (st - 2 >= s_min) STAGE(st - 2);   // slot free since iter st+1's barrier

    const bool allinv = (st * 64 > q0 + 31);   // tile entirely above diagonal
    if (!allinv) {
      const int bs = st % 3;
      const char* Ksb = (const char*)Ks[bs];
      const char* Vsb = (const char*)Vs[bs];
      const float alpha = __expf(lgq - lgp[st * 64]);
      const bool domask = (st * 64 + 63 > q0);
      const int qrel = qg - st * 64;
#pragma unroll
      for (int sblk = 0; sblk < 2; ++sblk) {
        f32x16 c = {};
        __builtin_amdgcn_s_setprio(1);
#pragma unroll
        for (int kk = 0; kk < 4; ++kk) {
          int row = sblk * 32 + l31;
          short8 kf = *(const short8*)(Ksb + row * 128 + (((kk * 2 + hi) ^ (row & 7)) << 4));
          c = __builtin_amdgcn_mfma_f32_32x32x16_bf16(kf, qf[kk], c, 0, 0, 0);
        }
        __builtin_amdgcn_s_setprio(0);
        if (domask) {   // diagonal tiles only (<=2 per wave): mask + pack
#pragma unroll
          for (int bq = 0; bq < 4; ++bq) {
            float p0 = c[bq * 4 + 0] * alpha, p1 = c[bq * 4 + 1] * alpha;
            float p2 = c[bq * 4 + 2] * alpha, p3 = c[bq * 4 + 3] * alpha;
            int s64 = sblk * 32 + bq * 8 + hi * 4;
            if (s64 + 0 > qrel) p0 = 0.f;
            if (s64 + 1 > qrel) p1 = 0.f;
            if (s64 + 2 > qrel) p2 = 0.f;
            if (s64 + 3 > qrel) p3 = 0.f;
            u32x2 pk; pk.x = cvtpk(p0, p1); pk.y = cvtpk(p2, p3);
            int slot = sblk * 4 + bq;
            *(u32x2*)(Pw + l31 * 128 + ((slot ^ psw) << 4) + hi * 8) = pk;
          }
        } else {        // interior tiles: pack only
#pragma unroll
          for (int bq = 0; bq < 4; ++bq) {
            u32x2 pk;
            pk.x = cvtpk(c[bq * 4 + 0] * alpha, c[bq * 4 + 1] * alpha);
            pk.y = cvtpk(c[bq * 4 + 2] * alpha, c[bq * 4 + 3] * alpha);
            int slot = sblk * 4 + bq;
            *(u32x2*)(Pw + l31 * 128 + ((slot ^ psw) << 4) + hi * 8) = pk;
          }
        }
      }
#pragma unroll
      for (int kk = 0; kk < 4; ++kk) {   // PV: Y[q 32][dd 64]
        short8 pf = *(const short8*)(Pw + l31 * 128 + (((kk * 2 + hi) ^ psw) << 4));
        short8 vf0 = *(const short8*)(Vsb + l31 * 128 + (((kk * 2 + hi) ^ (l31 & 7)) << 4));
        short8 vf1 = *(const short8*)(Vsb + (32 + l31) * 128 + (((kk * 2 + hi) ^ (l31 & 7)) << 4));
        __builtin_amdgcn_s_setprio(1);
        yacc0 = __builtin_amdgcn_mfma_f32_32x32x16_bf16(pf, vf0, yacc0, 0, 0, 0);
        yacc1 = __builtin_amdgcn_mfma_f32_32x32x16_bf16(pf, vf1, yacc1, 0, 0, 0);
        __builtin_amdgcn_s_setprio(0);
      }
    }
  }

#pragma unroll
  for (int reg = 0; reg < 16; ++reg) {
    int qrow = (reg & 3) + 8 * (reg >> 2) + 4 * hi;
    size_t rowg = (size_t)(b * T_) + qb * 128 + w * 32 + qrow;
    Y[rowg * INNER_ + h * 64 + l31] = f2bf(yacc0[reg]);
    Y[rowg * INNER_ + h * 64 + 32 + l31] = f2bf(yacc1[reg]);
  }
}

// ---------------------------------------------------------------------------
extern "C" void kernel_launch(void* const* d_in, const int* in_sizes, int n_in,
                              void* d_out, int out_size, void* d_ws, size_t ws_size,
                              hipStream_t stream) {
  const float* x        = (const float*)d_in[0];
  const float* W_qkv    = (const float*)d_in[1];
  const float* W_out    = (const float*)d_in[2];
  const float* W_dt     = (const float*)d_in[3];
  const float* b_dt     = (const float*)d_in[4];
  const float* W_gsp    = (const float*)d_in[5];
  const float* b_gsp    = (const float*)d_in[6];
  const float* inv_freq = (const float*)d_in[7];
  float* out = (float*)d_out;

  const int M = B_ * T_;  // 4096
  char* p = (char*)d_ws;
  auto alloc = [&](size_t bytes) {
    char* r = p; p += (bytes + 255) & ~(size_t)255; return r;
  };
  u16*    xb    = (u16*)alloc((size_t)M * D_ * 2);             // 8 MB
  u16*    Wcombt= (u16*)alloc((size_t)NC_ * D_ * 2);           // 8 MB
  u16*    Woutt = (u16*)alloc((size_t)D_ * INNER_ * 2);        // 2 MB
  u16*    Wdtb  = (u16*)alloc((size_t)H_ * D_ * 2);            // 32 KB
  u16*    Cqkvp = (u16*)alloc((size_t)M * NC_ * 2);            // 32 MB
  u16*    Qb    = (u16*)alloc((size_t)B_ * H_ * T_ * 64 * 2);  // 8 MB
  u16*    Kb    = (u16*)alloc((size_t)B_ * H_ * T_ * 64 * 2);
  u16*    Vb    = (u16*)alloc((size_t)B_ * H_ * T_ * 64 * 2);
  float*  lg    = (float*)alloc((size_t)B_ * H_ * T_ * 4);
  float*  lgc   = (float*)alloc((size_t)B_ * H_ * T_ * 4);
  float2* tab   = (float2*)alloc((size_t)T_ * 32 * 8);         // 512 KB
  // after pointwise, Cqkvp is dead -> alias attention buffers into it
  u16*    Vtg   = Cqkvp;                                       // 8 MB
  u16*    Yb    = Cqkvp + (size_t)4 * 1024 * 1024;             // 8 MB

  // fused prep (casts, transposes, rope table)
  prep_kernel<<<2624, 256, 0, stream>>>(x, W_qkv, W_gsp, W_out, W_dt, inv_freq,
                                        xb, Wcombt, Woutt, Wdtb, tab);
  // combined projection GEMM: [q|k|v|praw] = x @ [W_qkv|W_gsp]  (N=4096)
  gemm_big<<<512, 256, 0, stream>>>(xb, Wcombt, Cqkvp);

  pointwise_kernel<<<M / 4, 256, 0, stream>>>(Cqkvp, xb, Wdtb, b_dt, b_gsp,
                                              tab, Qb, Kb, Vb, lg);
  // merged scan + kv_prep (scan_kernel eliminated)
  kv_prep_kernel<<<dim3(T_ / 64, B_ * H_), 256, 0, stream>>>(Vb, lg, lgc, Vtg);

  attn_mfma<<<512, 256, 0, stream>>>(Qb, Kb, Vtg, lgc, Yb);

  // out = Y @ W_out  (fp32 out)
  gemm_bt<false><<<256, 256, 0, stream>>>(Yb, Woutt, out, M, D_, INNER_);
}

// Round 16
// 144.501 us; speedup vs baseline: 1.0616x; 1.0275x over previous
//
#include <hip/hip_runtime.h>
#include <hip/hip_bf16.h>
#include <math.h>

#define B_     2
#define T_     2048
#define D_     1024
#define H_     16
#define INNER_ 1024
#define NC_    4096       // combined GEMM N: 3072 qkv + 1024 gsp
#define SCALE_ 0.125f     // 64^-0.5, folded into Q at pointwise

typedef unsigned short u16;
typedef short short8 __attribute__((ext_vector_type(8)));
typedef float f32x4 __attribute__((ext_vector_type(4)));
typedef float f32x16 __attribute__((ext_vector_type(16)));
typedef unsigned short u16x4 __attribute__((ext_vector_type(4)));
typedef unsigned int u32x2 __attribute__((ext_vector_type(2)));

__device__ __forceinline__ u16 f2bf(float x) {
  union { float f; unsigned u; } v; v.f = x;
  unsigned r = v.u + 0x7fffu + ((v.u >> 16) & 1u);   // RNE, finite inputs
  return (u16)(r >> 16);
}
__device__ __forceinline__ float b2f(u16 x) {
  union { unsigned u; float f; } v; v.u = ((unsigned)x) << 16;
  return v.f;
}
// pack 2 f32 -> 2 bf16 in one VALU op (RNE)
__device__ __forceinline__ unsigned cvtpk(float lo, float hi) {
  unsigned r;
  asm("v_cvt_pk_bf16_f32 %0, %1, %2" : "=v"(r) : "v"(lo), "v"(hi));
  return r;
}
// async global->LDS, 16B per lane; LDS dest = wave-uniform base + lane*16
__device__ __forceinline__ void gload16(const void* g, void* l) {
  __builtin_amdgcn_global_load_lds(
      (const __attribute__((address_space(1))) void*)g,
      (__attribute__((address_space(3))) void*)l, 16, 0, 0);
}

// ---------------------------------------------------------------------------
// fused prep: [0,1280) weight transposes | [1280,1344) wdt | [1344,1600) rope
// | [1600,2624) cast x.  All branches block-uniform.
// ---------------------------------------------------------------------------
__global__ __launch_bounds__(256) void prep_kernel(
    const float* __restrict__ x, const float* __restrict__ W_qkv,
    const float* __restrict__ W_gsp, const float* __restrict__ W_out,
    const float* __restrict__ W_dt, const float* __restrict__ inv_freq,
    u16* __restrict__ xb, u16* __restrict__ Wcombt, u16* __restrict__ Woutt,
    u16* __restrict__ Wdtb, float2* __restrict__ tab) {
  const int bid = blockIdx.x, tid = threadIdx.x;
  if (bid < 1280) {   // 64x64 cast-transpose tiles, K=1024
    const float* src; u16* dst; int N, nx, ky;
    if (bid < 768)       { src = W_qkv; dst = Wcombt;                N = 3072; nx = bid % 48;          ky = bid / 48; }
    else if (bid < 1024) { src = W_gsp; dst = Wcombt + 3072 * 1024;  N = 1024; nx = (bid - 768) % 16;  ky = (bid - 768) / 16; }
    else                 { src = W_out; dst = Woutt;                 N = 1024; nx = (bid - 1024) % 16; ky = (bid - 1024) / 16; }
    __shared__ float tile[64][65];
    const int k0 = ky * 64, n0 = nx * 64;
    for (int e = tid; e < 4096; e += 256) {
      int kk = e >> 6, nn = e & 63;
      tile[kk][nn] = src[(size_t)(k0 + kk) * N + n0 + nn];
    }
    __syncthreads();
    for (int e = tid; e < 4096; e += 256) {
      int nn = e >> 6, kk = e & 63;
      dst[(size_t)(n0 + nn) * 1024 + k0 + kk] = f2bf(tile[kk][nn]);
    }
  } else if (bid < 1344) {   // W_dt [1024][16] -> Wdtb [16][1024]
    int i = (bid - 1280) * 256 + tid;
    int k = i >> 4, h = i & 15;
    Wdtb[(size_t)h * D_ + k] = f2bf(W_dt[i]);
  } else if (bid < 1600) {   // rope table
    int i = (bid - 1344) * 256 + tid;
    int t = i >> 5, j = i & 31;
    float s, c;
    sincosf((float)t * inv_freq[j], &s, &c);
    tab[i] = make_float2(c, s);
  } else {                   // cast x -> bf16, 4 float4 per thread
    int base = (bid - 1600) * 1024 + tid;
#pragma unroll
    for (int r = 0; r < 4; ++r) {
      int i = base + r * 256;
      float4 v = *reinterpret_cast<const float4*>(x + (size_t)i * 4);
      u16x4 o; o.x = f2bf(v.x); o.y = f2bf(v.y); o.z = f2bf(v.z); o.w = f2bf(v.w);
      *reinterpret_cast<u16x4*>(xb + (size_t)i * 4) = o;
    }
  }
}

// ---------------------------------------------------------------------------
// Big pipelined GEMM v4b (frozen): C(4096 x 4096) = A @ Bt^T, bf16 out.
// 128x256 tile, BK=32, 4 waves, 2 LDS slots (48KB), grid 512 = 2 blocks/CU.
// Rigorous sync: {vmcnt(0 own) -> barrier -> stage(kt+1) -> compute(kt)}.
// ---------------------------------------------------------------------------
__global__ __launch_bounds__(256, 2) void gemm_big(
    const u16* __restrict__ A, const u16* __restrict__ Bt,
    u16* __restrict__ C) {
  __shared__ u16 As[2][128 * 32] __attribute__((aligned(16)));  // 8KB each
  __shared__ u16 Bs[2][256 * 32] __attribute__((aligned(16)));  // 16KB each
  const int tid = threadIdx.x;
  const int w = tid >> 6, l = tid & 63;
  const int bid = blockIdx.x;             // 512 blocks: 32 brow x 16 bcol
  const int xcd = bid & 7, idx = bid >> 3;
  const int brow = xcd * 4 + (idx & 3);
  const int bcol = idx >> 2;
  const int m0 = brow * 128, n0 = bcol * 256;
  const int ql = l & 15, g4 = l >> 4;
  const int srow = tid >> 2;                // 0..63 (staging row within chunk)
  const int ssl  = (tid & 3) ^ (srow & 3);  // pre-swizzled k-slot

  const u16* Ag = A + (size_t)m0 * D_;
  const u16* Bg = Bt + (size_t)n0 * D_;

  auto STAGE = [&](int kt, int bp) {   // 6 gload16 per thread
#pragma unroll
    for (int c = 0; c < 2; ++c)
      gload16(Ag + (size_t)(c * 64 + srow) * D_ + kt * 32 + ssl * 8,
              (char*)As[bp] + c * 4096 + tid * 16);
#pragma unroll
    for (int c = 0; c < 4; ++c)
      gload16(Bg + (size_t)(c * 64 + srow) * D_ + kt * 32 + ssl * 8,
              (char*)Bs[bp] + c * 4096 + tid * 16);
  };

  f32x4 acc[8][4] = {};
  STAGE(0, 0);

  const int NT = D_ / 32;   // 32
  for (int kt = 0; kt < NT; ++kt) {
    const int bp = kt & 1;
    asm volatile("s_waitcnt vmcnt(0)" ::: "memory");   // own kt loads done
    __builtin_amdgcn_sched_barrier(0);
    __builtin_amdgcn_s_barrier();                      // => everyone's done
    __builtin_amdgcn_sched_barrier(0);
    if (kt + 1 < NT) STAGE(kt + 1, bp ^ 1);            // overlap with compute

    const char* Asb = (const char*)As[bp];
    const char* Bsb = (const char*)Bs[bp];
    short8 bf[4], af[4];
#pragma unroll
    for (int nf = 0; nf < 4; ++nf) {
      int row = w * 64 + nf * 16 + ql;
      bf[nf] = *(const short8*)(Bsb + row * 64 + ((g4 ^ (row & 3)) << 4));
    }
#pragma unroll
    for (int mf = 0; mf < 4; ++mf) {
      int row = mf * 16 + ql;
      af[mf] = *(const short8*)(Asb + row * 64 + ((g4 ^ (row & 3)) << 4));
    }
    __builtin_amdgcn_s_setprio(1);
#pragma unroll
    for (int mf = 0; mf < 4; ++mf)
#pragma unroll
      for (int nf = 0; nf < 4; ++nf)
        acc[mf][nf] = __builtin_amdgcn_mfma_f32_16x16x32_bf16(af[mf], bf[nf], acc[mf][nf], 0, 0, 0);
    __builtin_amdgcn_s_setprio(0);
#pragma unroll
    for (int mf = 0; mf < 4; ++mf) {
      int row = 64 + mf * 16 + ql;
      af[mf] = *(const short8*)(Asb + row * 64 + ((g4 ^ (row & 3)) << 4));
    }
    __builtin_amdgcn_s_setprio(1);
#pragma unroll
    for (int mf = 0; mf < 4; ++mf)
#pragma unroll
      for (int nf = 0; nf < 4; ++nf)
        acc[mf + 4][nf] = __builtin_amdgcn_mfma_f32_16x16x32_bf16(af[mf], bf[nf], acc[mf + 4][nf], 0, 0, 0);
    __builtin_amdgcn_s_setprio(0);
  }

#pragma unroll
  for (int mf = 0; mf < 8; ++mf) {
#pragma unroll
    for (int r = 0; r < 4; ++r) {
      size_t row = (size_t)(m0 + mf * 16 + g4 * 4 + r);
      size_t base = row * NC_ + n0 + w * 64 + ql;
#pragma unroll
      for (int nf = 0; nf < 4; ++nf)
        C[base + nf * 16] = f2bf(acc[mf][nf][r]);
    }
  }
}

// ---------------------------------------------------------------------------
// out-proj GEMM v3: out(4096 x 1024) = Y @ Woutt^T, fp32 out.
// 128x64 tile, BK=64, 4 waves (each 32x64), 2 slots (48KB LDS),
// grid 512 = 2 blocks/CU (cross-block overlap). Rigorous 1-barrier pipeline.
// ---------------------------------------------------------------------------
__global__ __launch_bounds__(256, 2) void gemm_out(
    const u16* __restrict__ A, const u16* __restrict__ Bt,
    float* __restrict__ Cv) {
  __shared__ u16 As[2][128 * 64] __attribute__((aligned(16)));  // 16KB each
  __shared__ u16 Bs[2][64 * 64] __attribute__((aligned(16)));   // 8KB each
  const int tid = threadIdx.x, w = tid >> 6, l = tid & 63;
  const int bid = blockIdx.x;             // 512 = 32 brow x 16 bcol
  const int xcd = bid & 7, idx = bid >> 3;
  const int brow = xcd * 4 + (idx & 3);
  const int bcol = idx >> 2;              // 0..15
  const int m0 = brow * 128, n0 = bcol * 64;
  const int ql = l & 15, g4 = l >> 4;
  const int srow = l >> 3;
  const int kgrp = ((l & 7) ^ srow) * 8;

  f32x4 acc[2][4] = {};

  auto stage = [&](int kt, int bs) {   // A: 16 chunks, B: 8 chunks (1KB each)
#pragma unroll
    for (int i = 0; i < 4; ++i) {
      int c = w * 4 + i;
      int row = c * 8 + srow;
      gload16(A + (size_t)(m0 + row) * INNER_ + kt * 64 + kgrp,
              (char*)As[bs] + c * 1024);
    }
#pragma unroll
    for (int i = 0; i < 2; ++i) {
      int c = w * 2 + i;
      int row = c * 8 + srow;
      gload16(Bt + (size_t)(n0 + row) * INNER_ + kt * 64 + kgrp,
              (char*)Bs[bs] + c * 1024);
    }
  };

  stage(0, 0);
  const int NT = INNER_ >> 6;   // 16
  for (int kt = 0; kt < NT; ++kt) {
    asm volatile("s_waitcnt vmcnt(0)" ::: "memory");   // own kt loads done
    __builtin_amdgcn_sched_barrier(0);
    __builtin_amdgcn_s_barrier();                      // all waves' kt done
    __builtin_amdgcn_sched_barrier(0);
    if (kt + 1 < NT) stage(kt + 1, (kt + 1) & 1);      // overlap with compute

    const char* Asb = (const char*)As[kt & 1];
    const char* Bsb = (const char*)Bs[kt & 1];
#pragma unroll
    for (int kk = 0; kk < 2; ++kk) {
      short8 af[2], bf[4];
#pragma unroll
      for (int mi = 0; mi < 2; ++mi) {
        int ra = w * 32 + mi * 16 + ql;
        int sa = kk * 4 + g4;
        af[mi] = *(const short8*)(Asb + ra * 128 + ((sa ^ (ra & 7)) << 4));
      }
#pragma unroll
      for (int nf = 0; nf < 4; ++nf) {
        int rb = nf * 16 + ql;
        int sa = kk * 4 + g4;
        bf[nf] = *(const short8*)(Bsb + rb * 128 + ((sa ^ (rb & 7)) << 4));
      }
      __builtin_amdgcn_s_setprio(1);
#pragma unroll
      for (int mi = 0; mi < 2; ++mi)
#pragma unroll
        for (int nf = 0; nf < 4; ++nf)
          acc[mi][nf] = __builtin_amdgcn_mfma_f32_16x16x32_bf16(af[mi], bf[nf], acc[mi][nf], 0, 0, 0);
      __builtin_amdgcn_s_setprio(0);
    }
  }
#pragma unroll
  for (int mi = 0; mi < 2; ++mi) {
#pragma unroll
    for (int r = 0; r < 4; ++r) {
      size_t row = (size_t)(m0 + w * 32 + mi * 16 + g4 * 4 + r);
      size_t base = row * D_ + n0 + ql;
#pragma unroll
      for (int nf = 0; nf < 4; ++nf)
        Cv[base + nf * 16] = acc[mi][nf][r];
    }
  }
}

// ---------------------------------------------------------------------------
// streaming pointwise + fused gamma: C [M][4096] = (q|k|v|praw). Wave/row.
// ---------------------------------------------------------------------------
__global__ __launch_bounds__(256) void pointwise_kernel(
    const u16* __restrict__ C, const u16* __restrict__ xb,
    const u16* __restrict__ Wdtb, const float* __restrict__ b_dt,
    const float* __restrict__ b_gsp, const float2* __restrict__ tab,
    u16* __restrict__ Qb, u16* __restrict__ Kb, u16* __restrict__ Vb,
    float* __restrict__ lg) {
  const int row = blockIdx.x * 4 + (threadIdx.x >> 6);
  const int l = threadIdx.x & 63;
  const int b = row >> 11, t = row & (T_ - 1);
  const int h = l >> 2;
  const int dd0 = (l & 3) * 16;
  const int col = h * 64 + dd0;
  const size_t cb = (size_t)row * NC_;

  // fused gamma
  float gsum = 0.f;
  {
    const int kc = (l & 3) * 256;
    const short8* xpg = (const short8*)(xb + (size_t)row * D_ + kc);
    const short8* wpg = (const short8*)(Wdtb + h * D_ + kc);
#pragma unroll
    for (int i = 0; i < 32; ++i) {
      short8 xv = xpg[i], wv = wpg[i];
#pragma unroll
      for (int j = 0; j < 8; ++j) gsum += b2f((u16)xv[j]) * b2f((u16)wv[j]);
    }
    gsum += __shfl_xor(gsum, 1);
    gsum += __shfl_xor(gsum, 2);
  }
  const float dtv = gsum + b_dt[h];
  const float sp = (dtv > 20.f) ? dtv : log1pf(__expf(dtv));
  const float gh = __expf(-sp);

  const short8* qp = (const short8*)(C + cb + col);
  const short8* kp = (const short8*)(C + cb + 1024 + col);
  const short8* vp = (const short8*)(C + cb + 2048 + col);
  const short8* pp = (const short8*)(C + cb + 3072 + col);
  short8 q0 = qp[0], q1 = qp[1];
  short8 k0 = kp[0], k1 = kp[1];
  short8 v0 = vp[0], v1 = vp[1];
  short8 pr0 = pp[0], pr1 = pp[1];

  float ge = 0.f;
  short8 vo0, vo1;
#pragma unroll
  for (int i = 0; i < 8; ++i) {
    float pv = b2f((u16)pr0[i]) + b_gsp[col + i];
    float p = 1.f / (1.f + __expf(-pv));
    ge += gh * (1.f - p) + p;
    vo0[i] = (short)f2bf(b2f((u16)v0[i]) * (1.f - p));
    float pv1 = b2f((u16)pr1[i]) + b_gsp[col + 8 + i];
    float p1 = 1.f / (1.f + __expf(-pv1));
    ge += gh * (1.f - p1) + p1;
    vo1[i] = (short)f2bf(b2f((u16)v1[i]) * (1.f - p1));
  }
  const size_t hm = (((size_t)(b * H_ + h)) * T_ + t) * 64 + dd0;
  ((short8*)(Vb + hm))[0] = vo0;
  ((short8*)(Vb + hm))[1] = vo1;

  ge += __shfl_xor(ge, 1);
  ge += __shfl_xor(ge, 2);
  if ((l & 3) == 0) {
    float gs = ge * (1.f / 64.f);
    gs = fminf(fmaxf(gs, 1e-6f), 1.f - 1e-6f);
    lg[((size_t)(b * H_ + h)) * T_ + t] = logf(gs);
  }

  short8 qo0, qo1, ko0, ko1;
  const float2* cs = tab + t * 32 + (dd0 >> 1);
#pragma unroll
  for (int m = 0; m < 4; ++m) {
    float2 c0 = cs[m];
    float qa = b2f((u16)q0[2 * m]), qb = b2f((u16)q0[2 * m + 1]);
    qo0[2 * m]     = (short)f2bf((qa * c0.x - qb * c0.y) * SCALE_);
    qo0[2 * m + 1] = (short)f2bf((qa * c0.y + qb * c0.x) * SCALE_);
    float ka = b2f((u16)k0[2 * m]), kb = b2f((u16)k0[2 * m + 1]);
    ko0[2 * m]     = (short)f2bf(ka * c0.x - kb * c0.y);
    ko0[2 * m + 1] = (short)f2bf(ka * c0.y + kb * c0.x);
    float2 c1 = cs[4 + m];
    float qa1 = b2f((u16)q1[2 * m]), qb1 = b2f((u16)q1[2 * m + 1]);
    qo1[2 * m]     = (short)f2bf((qa1 * c1.x - qb1 * c1.y) * SCALE_);
    qo1[2 * m + 1] = (short)f2bf((qa1 * c1.y + qb1 * c1.x) * SCALE_);
    float ka1 = b2f((u16)k1[2 * m]), kb1 = b2f((u16)k1[2 * m + 1]);
    ko1[2 * m]     = (short)f2bf(ka1 * c1.x - kb1 * c1.y);
    ko1[2 * m + 1] = (short)f2bf(ka1 * c1.y + kb1 * c1.x);
  }
  ((short8*)(Qb + hm))[0] = qo0; ((short8*)(Qb + hm))[1] = qo1;
  ((short8*)(Kb + hm))[0] = ko0; ((short8*)(Kb + hm))[1] = ko1;
}

// ---------------------------------------------------------------------------
// scan+kv_prep merged: block (stile, bh). Redundant in-block scan of lg;
// stile==0 writes lgc; all blocks build Vtg[bh][stile] = V*beta (V^T tiles).
// ---------------------------------------------------------------------------
__global__ __launch_bounds__(256) void kv_prep_kernel(
    const u16* __restrict__ Vb, const float* __restrict__ lg,
    float* __restrict__ lgc, u16* __restrict__ Vtg) {
  const int stile = blockIdx.x;
  const int bh = blockIdx.y;
  const int tid = threadIdx.x;
  __shared__ u16 vt[64][72];
  __shared__ float sums[256];
  __shared__ float lgs[T_];
  const size_t lbase = (size_t)bh * T_;

  float loc[8];
  {
    float run = 0.f;
#pragma unroll
    for (int i = 0; i < 8; ++i) { run += lg[lbase + tid * 8 + i]; loc[i] = run; }
    sums[tid] = run;
  }
  __syncthreads();
  if (tid == 0) {
    float r = 0.f;
    for (int i = 0; i < 256; ++i) { float v = sums[i]; sums[i] = r; r += v; }
  }
  __syncthreads();
  {
    const float off = sums[tid];
#pragma unroll
    for (int i = 0; i < 8; ++i) lgs[tid * 8 + i] = off + loc[i];
  }
  __syncthreads();
  if (stile == 0) {
#pragma unroll
    for (int i = 0; i < 8; ++i) lgc[lbase + tid * 8 + i] = lgs[tid * 8 + i];
  }

  const size_t base = (lbase + (size_t)stile * 64) * 64;
  const float lgb = lgs[stile * 64];
#pragma unroll
  for (int i = 0; i < 2; ++i) {
    int c = tid * 2 + i;
    int row = c >> 3, k8 = (c & 7) * 8;
    float beta = __expf(lgb - lgs[stile * 64 + row]);
    short8 vv = *(const short8*)(Vb + base + row * 64 + k8);
#pragma unroll
    for (int j = 0; j < 8; ++j) vt[row][k8 + j] = f2bf(b2f((u16)vv[j]) * beta);
  }
  __syncthreads();
#pragma unroll
  for (int i = 0; i < 2; ++i) {
    int c = tid * 2 + i;
    int dd = c >> 3, t8 = (c & 7) * 8;
    short8 o;
#pragma unroll
    for (int j = 0; j < 8; ++j) o[j] = (short)vt[t8 + j][dd];
    *(short8*)(Vtg + ((size_t)(bh * 32 + stile) * 64 + dd) * 64 + t8) = o;
  }
}

// ---------------------------------------------------------------------------
// MFMA attention v5r (frozen): 32x32x16, QBLK=128, 3-slot ring (48KB),
// rigorous sync, per-wave Ps LDS, cvt_pk pack, diagonal-only mask, s_min
// window, complementary-qb CU pairing.
// ---------------------------------------------------------------------------
__global__ __launch_bounds__(256) void attn_mfma(
    const u16* __restrict__ Qb, const u16* __restrict__ Kb,
    const u16* __restrict__ Vtg, const float* __restrict__ lgc,
    u16* __restrict__ Y) {
  const int i = blockIdx.x;            // 512
  const int xcd = i & 7;
  const int half = i >> 8;             // complementary halves share a CU
  const int r = (i >> 3) & 31;
  const int q8 = r >> 2;
  const int bh_hi = r & 3;
  const int qb = half ? (15 - q8) : q8;
  const int bh = xcd + (bh_hi << 3);
  const int b = bh >> 4, h = bh & 15;
  const int tid = threadIdx.x, w = tid >> 6, l = tid & 63;
  const int l31 = l & 31, hi = l >> 5;
  __shared__ u16 Ks[3][64 * 64] __attribute__((aligned(16)));
  __shared__ u16 Vs[3][64 * 64] __attribute__((aligned(16)));
  __shared__ u16 Ps[4][2048] __attribute__((aligned(16)));   // per-wave 32x64
  const u16* Qg = Qb + (size_t)bh * T_ * 64;
  const u16* Kg = Kb + (size_t)bh * T_ * 64;
  const u16* Vg = Vtg + (size_t)bh * 32 * 4096;
  const float* lgp = lgc + (size_t)bh * T_;
  const int srow = l >> 3, slot8 = l & 7;

  const int q0 = qb * 128 + w * 32;     // wave q base
  const int qg = q0 + l31;              // lane q row
  short8 qf[4];                          // Q B-frags: col=q, k=kk*16+hi*8
#pragma unroll
  for (int kk = 0; kk < 4; ++kk)
    qf[kk] = *(const short8*)(Qg + (size_t)qg * 64 + kk * 16 + hi * 8);
  const float lgq = lgp[qg];
  const float lgtop = lgp[qb * 128];

  char* Pw = (char*)Ps[w];
  const int psw = l31 & 7;

  f32x16 yacc0 = {}, yacc1 = {};

  const int st0 = qb * 2 + 1;
  int s_min;
  {
    int lo = 0, hic = st0;
    while (lo < hic) {
      int mid = (lo + hic) >> 1;
      if (lgtop - lgp[mid * 64 + 63] > -20.f) hic = mid; else lo = mid + 1;
    }
    s_min = lo;
  }

  auto STAGE = [&](int s) {   // 4 gloads/thread
    const int bs = s % 3;
#pragma unroll
    for (int i2 = 0; i2 < 2; ++i2) {
      int c = w * 2 + i2, row = c * 8 + srow;
      int kg = (slot8 ^ (row & 7)) * 8;
      gload16(Kg + (size_t)(s * 64 + row) * 64 + kg, (char*)Ks[bs] + c * 1024);
      gload16(Vg + (size_t)s * 4096 + row * 64 + kg, (char*)Vs[bs] + c * 1024);
    }
  };

  STAGE(st0);
  if (st0 - 1 >= s_min) STAGE(st0 - 1);

  for (int st = st0; st >= s_min; --st) {
    if (st - 1 >= s_min) asm volatile("s_waitcnt vmcnt(4)" ::: "memory");
    else                 asm volatile("s_waitcnt vmcnt(0)" ::: "memory");
    __builtin_amdgcn_sched_barrier(0);
    __builtin_amdgcn_s_barrier();
    __builtin_amdgcn_sched_barrier(0);
    if (st - 2 >= s_min) STAGE(st - 2);   // slot free since iter st+1's barrier

    const bool allinv = (st * 64 > q0 + 31);   // tile entirely above diagonal
    if (!allinv) {
      const int bs = st % 3;
      const char* Ksb = (const char*)Ks[bs];
      const char* Vsb = (const char*)Vs[bs];
      const float alpha = __expf(lgq - lgp[st * 64]);
      const bool domask = (st * 64 + 63 > q0);
      const int qrel = qg - st * 64;
#pragma unroll
      for (int sblk = 0; sblk < 2; ++sblk) {
        f32x16 c = {};
        __builtin_amdgcn_s_setprio(1);
#pragma unroll
        for (int kk = 0; kk < 4; ++kk) {
          int row = sblk * 32 + l31;
          short8 kf = *(const short8*)(Ksb + row * 128 + (((kk * 2 + hi) ^ (row & 7)) << 4));
          c = __builtin_amdgcn_mfma_f32_32x32x16_bf16(kf, qf[kk], c, 0, 0, 0);
        }
        __builtin_amdgcn_s_setprio(0);
        if (domask) {   // diagonal tiles only (<=2 per wave): mask + pack
#pragma unroll
          for (int bq = 0; bq < 4; ++bq) {
            float p0 = c[bq * 4 + 0] * alpha, p1 = c[bq * 4 + 1] * alpha;
            float p2 = c[bq * 4 + 2] * alpha, p3 = c[bq * 4 + 3] * alpha;
            int s64 = sblk * 32 + bq * 8 + hi * 4;
            if (s64 + 0 > qrel) p0 = 0.f;
            if (s64 + 1 > qrel) p1 = 0.f;
            if (s64 + 2 > qrel) p2 = 0.f;
            if (s64 + 3 > qrel) p3 = 0.f;
            u32x2 pk; pk.x = cvtpk(p0, p1); pk.y = cvtpk(p2, p3);
            int slot = sblk * 4 + bq;
            *(u32x2*)(Pw + l31 * 128 + ((slot ^ psw) << 4) + hi * 8) = pk;
          }
        } else {        // interior tiles: pack only
#pragma unroll
          for (int bq = 0; bq < 4; ++bq) {
            u32x2 pk;
            pk.x = cvtpk(c[bq * 4 + 0] * alpha, c[bq * 4 + 1] * alpha);
            pk.y = cvtpk(c[bq * 4 + 2] * alpha, c[bq * 4 + 3] * alpha);
            int slot = sblk * 4 + bq;
            *(u32x2*)(Pw + l31 * 128 + ((slot ^ psw) << 4) + hi * 8) = pk;
          }
        }
      }
#pragma unroll
      for (int kk = 0; kk < 4; ++kk) {   // PV: Y[q 32][dd 64]
        short8 pf = *(const short8*)(Pw + l31 * 128 + (((kk * 2 + hi) ^ psw) << 4));
        short8 vf0 = *(const short8*)(Vsb + l31 * 128 + (((kk * 2 + hi) ^ (l31 & 7)) << 4));
        short8 vf1 = *(const short8*)(Vsb + (32 + l31) * 128 + (((kk * 2 + hi) ^ (l31 & 7)) << 4));
        __builtin_amdgcn_s_setprio(1);
        yacc0 = __builtin_amdgcn_mfma_f32_32x32x16_bf16(pf, vf0, yacc0, 0, 0, 0);
        yacc1 = __builtin_amdgcn_mfma_f32_32x32x16_bf16(pf, vf1, yacc1, 0, 0, 0);
        __builtin_amdgcn_s_setprio(0);
      }
    }
  }

#pragma unroll
  for (int reg = 0; reg < 16; ++reg) {
    int qrow = (reg & 3) + 8 * (reg >> 2) + 4 * hi;
    size_t rowg = (size_t)(b * T_) + qb * 128 + w * 32 + qrow;
    Y[rowg * INNER_ + h * 64 + l31] = f2bf(yacc0[reg]);
    Y[rowg * INNER_ + h * 64 + 32 + l31] = f2bf(yacc1[reg]);
  }
}

// ---------------------------------------------------------------------------
extern "C" void kernel_launch(void* const* d_in, const int* in_sizes, int n_in,
                              void* d_out, int out_size, void* d_ws, size_t ws_size,
                              hipStream_t stream) {
  const float* x        = (const float*)d_in[0];
  const float* W_qkv    = (const float*)d_in[1];
  const float* W_out    = (const float*)d_in[2];
  const float* W_dt     = (const float*)d_in[3];
  const float* b_dt     = (const float*)d_in[4];
  const float* W_gsp    = (const float*)d_in[5];
  const float* b_gsp    = (const float*)d_in[6];
  const float* inv_freq = (const float*)d_in[7];
  float* out = (float*)d_out;

  const int M = B_ * T_;  // 4096
  char* p = (char*)d_ws;
  auto alloc = [&](size_t bytes) {
    char* r = p; p += (bytes + 255) & ~(size_t)255; return r;
  };
  u16*    xb    = (u16*)alloc((size_t)M * D_ * 2);             // 8 MB
  u16*    Wcombt= (u16*)alloc((size_t)NC_ * D_ * 2);           // 8 MB
  u16*    Woutt = (u16*)alloc((size_t)D_ * INNER_ * 2);        // 2 MB
  u16*    Wdtb  = (u16*)alloc((size_t)H_ * D_ * 2);            // 32 KB
  u16*    Cqkvp = (u16*)alloc((size_t)M * NC_ * 2);            // 32 MB
  u16*    Qb    = (u16*)alloc((size_t)B_ * H_ * T_ * 64 * 2);  // 8 MB
  u16*    Kb    = (u16*)alloc((size_t)B_ * H_ * T_ * 64 * 2);
  u16*    Vb    = (u16*)alloc((size_t)B_ * H_ * T_ * 64 * 2);
  float*  lg    = (float*)alloc((size_t)B_ * H_ * T_ * 4);
  float*  lgc   = (float*)alloc((size_t)B_ * H_ * T_ * 4);
  float2* tab   = (float2*)alloc((size_t)T_ * 32 * 8);         // 512 KB
  // after pointwise, Cqkvp is dead -> alias attention buffers into it
  u16*    Vtg   = Cqkvp;                                       // 8 MB
  u16*    Yb    = Cqkvp + (size_t)4 * 1024 * 1024;             // 8 MB

  // fused prep (casts, transposes, rope table)
  prep_kernel<<<2624, 256, 0, stream>>>(x, W_qkv, W_gsp, W_out, W_dt, inv_freq,
                                        xb, Wcombt, Woutt, Wdtb, tab);
  // combined projection GEMM: [q|k|v|praw] = x @ [W_qkv|W_gsp]  (N=4096)
  gemm_big<<<512, 256, 0, stream>>>(xb, Wcombt, Cqkvp);

  pointwise_kernel<<<M / 4, 256, 0, stream>>>(Cqkvp, xb, Wdtb, b_dt, b_gsp,
                                              tab, Qb, Kb, Vb, lg);
  // merged scan + kv_prep
  kv_prep_kernel<<<dim3(T_ / 64, B_ * H_), 256, 0, stream>>>(Vb, lg, lgc, Vtg);

  attn_mfma<<<512, 256, 0, stream>>>(Qb, Kb, Vtg, lgc, Yb);

  // out = Y @ W_out  (fp32 out), 128x64 tiles -> 2 blocks/CU
  gemm_out<<<512, 256, 0, stream>>>(Yb, Woutt, out);
}